// Round 9
// baseline (252.622 us; speedup 1.0000x reference)
//
#include <hip/hip_runtime.h>
#include <math.h>

namespace {
constexpr int kT = 16;
constexpr int kH = 56;
constexpr int kW = 56;
constexpr int kCAll = 256;
constexpr int kPlane = kH * kW;      // 3136
constexpr int kPlane4 = kPlane / 4;  // 784
}

// Gate layout (fp32, stored in out[frame 127]): plane index (n*2+g)*16 + t,
// each plane kPlane floats. Total = 256 planes = exactly one output frame.

// K1: gate = tanh(conv3d(relu(bn(x[:, :64])), groups=2) + b)
// Grid 512 = (n:8, t:16, g:2, stripe:2); block = 512 threads = 8 waves.
// Wave w owns ic = w*4..w*4+3 (x kd=3 -> 12 slices), staged into a
// WAVE-PRIVATE LDS buffer (30 rows x 16 float4-blocks, idx XOR (row&15)).
// NO manual fences/sched_barriers (r8's m141 mistake): plain LDS accesses;
// the compiler inserts counted lgkmcnt waits and is free to pipeline
// across slices. Only 2 block barriers total (final cross-wave reduction).
__global__ __launch_bounds__(512, 4)
void gate_conv_kernel(const float* __restrict__ x,
                      const float* __restrict__ gamma,
                      const float* __restrict__ beta,
                      const float* __restrict__ mean,
                      const float* __restrict__ var,
                      const float* __restrict__ cw,
                      const float* __restrict__ cb,
                      float* __restrict__ gate) {
  __shared__ float4 sm4[8 * 480];      // 8 waves x (30 rows x 16 blocks)

  const int bid = blockIdx.x;          // (((n*16+t)*2+g)*2+stripe)
  const int stripe = bid & 1;
  const int g = (bid >> 1) & 1;
  const int t = (bid >> 2) & 15;
  const int n = bid >> 6;              // 0..7
  const int h0 = stripe * 28;
  const int tid = threadIdx.x;
  const int wid = tid >> 6;            // wave 0..7
  const int lane = tid & 63;
  const int r = lane >> 1;             // 0..31 (active < 28)
  const int h = lane & 1;              // column half
  const int wb = wid * 480;            // wave LDS base (float4 units)

  // WAVE-PRIVATE zero init (halo rows/slots stay zero forever).
  for (int i = lane; i < 480; i += 64)
    sm4[wb + i] = make_float4(0.f, 0.f, 0.f, 0.f);

  // Precomputed staging map: up to 7 strided (row, block) slots per lane.
  int rr_u[7], fb_u[7], go_u[7];       // LDS row, LDS block, global offset
  bool val_u[7];
  #pragma unroll
  for (int u = 0; u < 7; ++u) {
    const int j = lane + u * 64;
    bool v = (j < 420);
    int rr = 0, fb = 0, go = 0;
    if (v) {
      rr = j / 14;
      fb = j - rr * 14;
      const int gr = h0 + rr - 1;
      v = ((unsigned)gr < (unsigned)kH);
      if (v) go = gr * 14 + fb;
    }
    rr_u[u] = rr; fb_u[u] = fb; go_u[u] = go; val_u[u] = v;
  }

  float acc[28];
  #pragma unroll
  for (int p = 0; p < 28; ++p) acc[p] = 0.f;

  for (int il = 0; il < 4; ++il) {
    const int ch = g * 32 + wid * 4 + il;
    const float sc = gamma[ch] * rsqrtf(var[ch] + 1e-5f);
    const float sh = beta[ch] - mean[ch] * sc;
    for (int kd = 0; kd < 3; ++kd) {
      const int tt = t + kd - 1;
      if (tt < 0 || tt >= kT) continue;          // block-uniform skip
      const float4* src4 =
          (const float4*)x + ((size_t)(n * kT + tt) * kCAll + ch) * kPlane4;
      // stage: global -> reg -> BN/ReLU -> wave-private LDS (swizzled)
      float4 stg[7];
      #pragma unroll
      for (int u = 0; u < 7; ++u)
        stg[u] = val_u[u] ? src4[go_u[u]] : make_float4(0.f, 0.f, 0.f, 0.f);
      #pragma unroll
      for (int u = 0; u < 7; ++u) {
        if (val_u[u]) {
          float4 a = stg[u];
          a.x = fmaxf(0.f, fmaf(a.x, sc, sh));
          a.y = fmaxf(0.f, fmaf(a.y, sc, sh));
          a.z = fmaxf(0.f, fmaf(a.z, sc, sh));
          a.w = fmaxf(0.f, fmaf(a.w, sc, sh));
          sm4[wb + rr_u[u] * 16 + ((fb_u[u] + 1) ^ (rr_u[u] & 15))] = a;
        }
      }
      // compiler-ordered LDS dependences (no fences, no sched pinning)
      if (r < 28) {
        const float* wbp = cw + ch * 27 + kd * 9;
        float wk[9];
        #pragma unroll
        for (int j = 0; j < 9; ++j) wk[j] = wbp[j];
        #pragma unroll
        for (int kh = 0; kh < 3; ++kh) {
          const int prow = r + kh;               // padded row 0..29
          const int swz = prow & 15;
          const int base = wb + prow * 16;
          float f[36];                           // px (28h-4) .. (28h+31)
          #pragma unroll
          for (int jj = 0; jj < 9; ++jj) {
            const float4 B = sm4[base + ((7 * h + jj) ^ swz)];
            f[4 * jj + 0] = B.x; f[4 * jj + 1] = B.y;
            f[4 * jj + 2] = B.z; f[4 * jj + 3] = B.w;
          }
          const float w0 = wk[kh * 3 + 0];
          const float w1 = wk[kh * 3 + 1];
          const float w2 = wk[kh * 3 + 2];
          #pragma unroll
          for (int p = 0; p < 28; ++p)
            acc[p] = fmaf(f[p + 3], w0,
                     fmaf(f[p + 4], w1, fmaf(f[p + 5], w2, acc[p])));
        }
      }
    }
  }

  // Cross-wave reduction: reuse sm4 as a float region [8][1568].
  __syncthreads();                               // all waves' compute done
  float* smf = (float*)sm4;
  if (r < 28) {
    const int q0 = r * 56 + h * 28;
    #pragma unroll
    for (int p = 0; p < 28; ++p) smf[wid * 1568 + q0 + p] = acc[p];
  }
  __syncthreads();
  const float bias = cb[g];
  float* gp = gate + ((size_t)(n * 2 + g) * kT + t) * kPlane + h0 * kW;
  for (int q = tid; q < 1568; q += 512) {
    float s = 0.f;
    #pragma unroll
    for (int w = 0; w < 8; ++w) s += smf[w * 1568 + q];
    gp[q] = tanhf(s + bias);
  }
}

// K1.5: copy the 3 gate planes frame-127 outputs need (g0[n7,t15]=239,
// g1[n7,t14]=254, g1[n7,t15]=255) into hole H = frame 126, channels 64..66.
__global__ __launch_bounds__(256)
void copy_gate_slice_kernel(float4* __restrict__ o4) {
  const int j = blockIdx.x * 256 + threadIdx.x;
  if (j >= 3 * kPlane4) return;
  const int q = j / kPlane4;
  const int rr = j - q * kPlane4;
  const int pidx = (q == 0) ? 239 : (q == 1 ? 254 : 255);
  const size_t G1 = (size_t)127 * kCAll * kPlane4;
  const size_t H = ((size_t)126 * kCAll + 64) * kPlane4;
  o4[H + j] = o4[G1 + (size_t)pidx * kPlane4 + rr];
}

// K2: frames 0..126. c>=64 passthrough (skip hole H); c<64 gated shift.
//   half0 (left):  out[t] = g0[t+1]*x[t+1] + x[t] - g0[t]*x[t]
//   half1 (right): out[t] = g1[t-1]*x[t-1] + x[t] - g1[t]*x[t]
//   channel regroup inverse: out k -> pre channel (k&1)*16 + (k>>1)
__global__ __launch_bounds__(256)
void shift_main_kernel(const float4* __restrict__ x4,
                       const float4* __restrict__ g4,
                       float4* __restrict__ o4) {
  const size_t total = (size_t)127 * kCAll * kPlane4;
  const size_t idx = (size_t)blockIdx.x * 256 + threadIdx.x;
  if (idx >= total) return;

  const int p = (int)(idx % kPlane4);
  const size_t rest = idx / kPlane4;
  const int c = (int)(rest % kCAll);
  const int f = (int)(rest / kCAll);

  if (c >= 64) {
    if (f == 126 && c <= 66) return;  // hole H holds gate slice until K3
    o4[idx] = x4[idx];
    return;
  }

  const int n = f >> 4;
  const int t = f & 15;
  const int half = c >> 5;
  const int k = c & 31;
  const int m = ((k & 1) << 4) + (k >> 1);
  const int src_ch = half * 32 + m;

  const size_t xcur = ((size_t)f * kCAll + src_ch) * kPlane4 + p;
  const size_t gbase = (size_t)(n * 2 + half) * kT * kPlane4 + p;

  const float4 xc = x4[xcur];
  const float4 gc = g4[gbase + (size_t)t * kPlane4];
  float4 y = make_float4(0.f, 0.f, 0.f, 0.f);
  if (half == 0) {
    if (t < kT - 1) {
      const float4 xn = x4[xcur + (size_t)kCAll * kPlane4];
      const float4 gn = g4[gbase + (size_t)(t + 1) * kPlane4];
      y.x = gn.x * xn.x; y.y = gn.y * xn.y; y.z = gn.z * xn.z; y.w = gn.w * xn.w;
    }
  } else {
    if (t > 0) {
      const float4 xp = x4[xcur - (size_t)kCAll * kPlane4];
      const float4 gp = g4[gbase + (size_t)(t - 1) * kPlane4];
      y.x = gp.x * xp.x; y.y = gp.y * xp.y; y.z = gp.z * xp.z; y.w = gp.w * xp.w;
    }
  }
  float4 res;
  res.x = y.x + (xc.x - gc.x * xc.x);
  res.y = y.y + (xc.y - gc.y * xc.y);
  res.z = y.z + (xc.z - gc.z * xc.z);
  res.w = y.w + (xc.w - gc.w * xc.w);
  o4[idx] = res;
}

// K3: frame 127 (n=7, t=15). Reads gate slices from hole H; overwrites the
// old gate region (frame 127) with final outputs.
__global__ __launch_bounds__(256)
void last_frame_kernel(const float4* __restrict__ x4,
                       float4* o4) {
  const int idx = blockIdx.x * 256 + threadIdx.x;
  if (idx >= kCAll * kPlane4) return;
  const size_t F127 = (size_t)127 * kCAll * kPlane4;
  const int p = idx % kPlane4;
  const int c = idx / kPlane4;
  if (c >= 64) { o4[F127 + idx] = x4[F127 + idx]; return; }

  const size_t H = ((size_t)126 * kCAll + 64) * kPlane4;
  const int half = c >> 5;
  const int k = c & 31;
  const int m = ((k & 1) << 4) + (k >> 1);
  const int src_ch = half * 32 + m;

  const float4 xc = x4[F127 + (size_t)src_ch * kPlane4 + p];
  float4 gc;
  float4 y = make_float4(0.f, 0.f, 0.f, 0.f);
  if (half == 0) {
    gc = o4[H + 0 * kPlane4 + p];                 // g0[t=15]; t+1 padded -> y=0
  } else {
    gc = o4[H + 2 * kPlane4 + p];                 // g1[t=15]
    const float4 gp = o4[H + 1 * kPlane4 + p];    // g1[t=14]
    const float4 xp = x4[((size_t)126 * kCAll + src_ch) * kPlane4 + p];
    y.x = gp.x * xp.x; y.y = gp.y * xp.y; y.z = gp.z * xp.z; y.w = gp.w * xp.w;
  }
  float4 res;
  res.x = y.x + (xc.x - gc.x * xc.x);
  res.y = y.y + (xc.y - gc.y * xc.y);
  res.z = y.z + (xc.z - gc.z * xc.z);
  res.w = y.w + (xc.w - gc.w * xc.w);
  o4[F127 + idx] = res;
}

// K4: hole H gets its real passthrough values.
__global__ __launch_bounds__(256)
void fix_hole_kernel(const float4* __restrict__ x4, float4* __restrict__ o4) {
  const int j = blockIdx.x * 256 + threadIdx.x;
  if (j >= 3 * kPlane4) return;
  const size_t H = ((size_t)126 * kCAll + 64) * kPlane4;
  o4[H + j] = x4[H + j];
}

extern "C" void kernel_launch(void* const* d_in, const int* in_sizes, int n_in,
                              void* d_out, int out_size, void* d_ws, size_t ws_size,
                              hipStream_t stream) {
  const float* x     = (const float*)d_in[0];
  const float* gamma = (const float*)d_in[1];
  const float* beta  = (const float*)d_in[2];
  const float* mean  = (const float*)d_in[3];
  const float* var   = (const float*)d_in[4];
  const float* cw    = (const float*)d_in[5];
  const float* cb    = (const float*)d_in[6];
  float* out = (float*)d_out;

  // Gate tensor lives in the frame-127 region of the output (exactly 1 frame).
  float* gate = out + (size_t)127 * kCAll * kPlane;

  // 8 n * 16 t * 2 g * 2 stripes = 512 blocks, 512 threads (8 waves)
  gate_conv_kernel<<<512, 512, 0, stream>>>(x, gamma, beta, mean, var, cw, cb, gate);
  copy_gate_slice_kernel<<<10, 256, 0, stream>>>((float4*)out);

  const size_t total4 = (size_t)127 * kCAll * kPlane4;  // 25,489,408
  shift_main_kernel<<<(unsigned)((total4 + 255) / 256), 256, 0, stream>>>(
      (const float4*)x, (const float4*)gate, (float4*)out);

  last_frame_kernel<<<(kCAll * kPlane4 + 255) / 256, 256, 0, stream>>>(
      (const float4*)x, (float4*)out);
  fix_hole_kernel<<<10, 256, 0, stream>>>((const float4*)x, (float4*)out);
}